// Round 8
// baseline (916.896 us; speedup 1.0000x reference)
//
#include <hip/hip_runtime.h>
#include <math.h>

// SequentialVAE on MI355X.
// R7 -> R8: same math & chain lengths (absmax-safe), two structural changes:
//  * riccati_wave2 / xseq_wave2: each 64-lane wave runs TWO independent chunks
//    interleaved (ILP-2) — at <1 wave/SIMD occupancy the serial chains are pure
//    latency; the sibling chunk fills the stalls. Per-chunk op order identical.
//  * K2's three N=256 GEMMs fused into one N=768 GEMM vs concatenated weights.
//
//  P0  X -> bf16; transpose->bf16 of W1; transpose WA/WBtop/WBbot into Wcat
//  K1  MFMA bf16 gemm: h = relu(X@W1+b1) -> bf16
//  K2  MFMA bf16 gemm: Ccat = h@[WA|WBt|WBb] (+bA on cols<256) -> fp32 [8192][768]
//      + mu = h@Wmu+bmu
//  K3  make_psd: AA_t, BB_t from Ccat slices
//  K4  riccati_wave2: 256 blocks x 2 chunks(S=16, W=64) interleaved
//  K5  chol_inv per t: L=chol(D), Linv=L^{-1}, C = BB Linv^T
//  K6  xseq_wave2: 128 blocks x 2 chunks(XS=32, XW=128) interleaved
//  K7  entropy = logdet + DX*T/2*(1+log(2pi))

#define T_STEPS 8192
#define DXX 1024

typedef __bf16 bf16x8 __attribute__((ext_vector_type(8)));
typedef float f32x4 __attribute__((ext_vector_type(4)));
typedef unsigned short u16x8 __attribute__((ext_vector_type(8)));
typedef unsigned short u16x4 __attribute__((ext_vector_type(4)));

#define DOT4(r, b) ((r).x*(b).x + (r).y*(b).y + (r).z*(b).z + (r).w*(b).w)

__device__ __forceinline__ unsigned short f2bf(float v) {
  unsigned int u = __float_as_uint(v);
  unsigned int r = (u + 0x7FFFu + ((u >> 16) & 1u)) >> 16;   // RN-even
  return (unsigned short)r;
}
__device__ __forceinline__ float bf2f(unsigned short b) {
  return __uint_as_float(((unsigned int)b) << 16);
}

// ---------------- P0a: elementwise fp32 -> bf16 ----------------
__global__ __launch_bounds__(256) void to_bf16(
    const float* __restrict__ src, unsigned short* __restrict__ dst, int n4)
{
  int idx = blockIdx.x * 256 + threadIdx.x;
  if (idx >= n4) return;
  float4 v = ((const float4*)src)[idx];
  u16x4 h;
  h[0] = f2bf(v.x); h[1] = f2bf(v.y); h[2] = f2bf(v.z); h[3] = f2bf(v.w);
  *(u16x4*)(dst + (size_t)idx * 4) = h;
}

// ---------------- P0b: transpose [K][N] -> [N][K] + bf16 ----------------
__global__ __launch_bounds__(256) void transpose_bf16(
    const float* __restrict__ W, unsigned short* __restrict__ Tt, int K, int N)
{
  __shared__ float tile[32][33];
  int k0 = blockIdx.x * 32, n0 = blockIdx.y * 32;
  int c = threadIdx.x & 31, r = threadIdx.x >> 5;  // r in 0..7
#pragma unroll
  for (int e = 0; e < 4; ++e)
    tile[r + 8 * e][c] = W[(size_t)(k0 + r + 8 * e) * N + n0 + c];
  __syncthreads();
#pragma unroll
  for (int e = 0; e < 4; ++e)
    Tt[(size_t)(n0 + r + 8 * e) * K + k0 + c] = f2bf(tile[c][r + 8 * e]);
}

// ---------------- K1/K2: MFMA bf16 GEMM ----------------
#define LDT 40

__global__ __launch_bounds__(256) void gemm_mfma(
    const unsigned short* __restrict__ Abf, const unsigned short* __restrict__ Bbf,
    const float* __restrict__ bias, int biasN, float* __restrict__ outF,
    unsigned short* __restrict__ outBf, int M, int N, int K, int mode)
{
  __shared__ __align__(16) unsigned short At[128 * LDT];
  __shared__ __align__(16) unsigned short Bt[128 * LDT];
  int tid = threadIdx.x;
  int l = tid & 63;
  int w = tid >> 6;
  int wm = w >> 1, wn = w & 1;
  int lane15 = l & 15, quad = l >> 4;
  int bm = blockIdx.y * 128, bn = blockIdx.x * 128;
  int srow = tid >> 1, shalf = tid & 1;
  const size_t aRowOff = (size_t)(bm + srow) * K;
  const size_t bRowOff = (size_t)(bn + srow) * K;

  f32x4 acc[4][4];
#pragma unroll
  for (int mi = 0; mi < 4; ++mi)
#pragma unroll
    for (int ni = 0; ni < 4; ++ni) acc[mi][ni] = (f32x4){0.f, 0.f, 0.f, 0.f};

  for (int k0 = 0; k0 < K; k0 += 32) {
    u16x8 a0 = *(const u16x8*)(Abf + aRowOff + k0 + shalf * 16);
    u16x8 a1 = *(const u16x8*)(Abf + aRowOff + k0 + shalf * 16 + 8);
    u16x8 b0 = *(const u16x8*)(Bbf + bRowOff + k0 + shalf * 16);
    u16x8 b1 = *(const u16x8*)(Bbf + bRowOff + k0 + shalf * 16 + 8);
    __syncthreads();
    *(u16x8*)&At[srow * LDT + shalf * 16] = a0;
    *(u16x8*)&At[srow * LDT + shalf * 16 + 8] = a1;
    *(u16x8*)&Bt[srow * LDT + shalf * 16] = b0;
    *(u16x8*)&Bt[srow * LDT + shalf * 16 + 8] = b1;
    __syncthreads();
    bf16x8 af[4], bfr[4];
#pragma unroll
    for (int mi = 0; mi < 4; ++mi)
      af[mi] = *(const bf16x8*)&At[(wm * 64 + mi * 16 + lane15) * LDT + quad * 8];
#pragma unroll
    for (int ni = 0; ni < 4; ++ni)
      bfr[ni] = *(const bf16x8*)&Bt[(wn * 64 + ni * 16 + lane15) * LDT + quad * 8];
#pragma unroll
    for (int mi = 0; mi < 4; ++mi)
#pragma unroll
      for (int ni = 0; ni < 4; ++ni)
        acc[mi][ni] = __builtin_amdgcn_mfma_f32_16x16x32_bf16(af[mi], bfr[ni], acc[mi][ni], 0, 0, 0);
  }

#pragma unroll
  for (int mi = 0; mi < 4; ++mi) {
#pragma unroll
    for (int ni = 0; ni < 4; ++ni) {
      int gc = bn + wn * 64 + ni * 16 + lane15;
      float bv = (bias && gc < biasN) ? bias[gc] : 0.f;
#pragma unroll
      for (int r = 0; r < 4; ++r) {
        int gr = bm + wm * 64 + mi * 16 + quad * 4 + r;
        float v = acc[mi][ni][r] + bv;
        if (mode == 1) {
          outBf[(size_t)gr * N + gc] = f2bf(fmaxf(v, 0.f));
        } else {
          outF[(size_t)gr * N + gc] = v;
        }
      }
    }
  }
}

// ---------------- K2b: mu = h @ Wmu + bmu ----------------
__global__ __launch_bounds__(256) void mu_gemm(
    const unsigned short* __restrict__ hbf, const float* __restrict__ Wmu,
    const float* __restrict__ bmu, float* __restrict__ mu)
{
  int idx = blockIdx.x * 256 + threadIdx.x;
  int t = idx >> 4, j = idx & 15;
  const u16x8* ph = (const u16x8*)(hbf + (size_t)t * 1024);
  float s = bmu[j];
#pragma unroll 2
  for (int k8 = 0; k8 < 128; ++k8) {
    u16x8 hv = ph[k8];
#pragma unroll
    for (int e = 0; e < 8; ++e)
      s = fmaf(bf2f(hv[e]), Wmu[(k8 * 8 + e) * 16 + j], s);
  }
  mu[idx] = s;
}

// ---------------- K3: AA_t, BB_t from Ccat (stride 768: A|Qtop|Qbot) ----------------
__global__ __launch_bounds__(256) void make_psd(
    const float* __restrict__ Ccat, const float* __restrict__ bB,
    float* __restrict__ AA, float* __restrict__ BBm, float* __restrict__ logdet)
{
  int t = blockIdx.x;
  int tid = threadIdx.x;
  int i = tid >> 4, j = tid & 15;
  if (t == 0 && tid == 0) *logdet = 0.f;
  __shared__ float a[16][17], bp[16][17], bq[16][17];
  a[i][j] = Ccat[(size_t)t * 768 + tid] + (i == j ? 1.f : 0.f);
  bp[i][j] = (t >= 1) ? (Ccat[(size_t)t * 768 + 256 + tid] + Ccat[(size_t)(t - 1) * 768 + 512 + tid] + bB[tid]) : 0.f;
  bool has_b = (t < T_STEPS - 1);
  if (has_b) bq[i][j] = Ccat[(size_t)(t + 1) * 768 + 256 + tid] + Ccat[(size_t)t * 768 + 512 + tid] + bB[tid];
  __syncthreads();
  float s = (i == j) ? 1e-6f : 0.f;
#pragma unroll
  for (int k = 0; k < 16; ++k) s += a[i][k] * a[j][k] + bp[i][k] * bp[j][k];
  AA[(size_t)t * 256 + tid] = s;
  if (has_b) {
    float s2 = 0.f;
#pragma unroll
    for (int k = 0; k < 16; ++k) s2 += bq[i][k] * a[j][k];
    BBm[(size_t)t * 256 + tid] = s2;
  }
}

// ---------------- wave-level 16x16 helpers ----------------
__device__ __forceinline__ void gj_inv(float dr[4], int l, int q, int c) {
#pragma unroll
  for (int k = 0; k < 16; ++k) {
    const int kq = k >> 2, ku = k & 3;
    float rowv = __shfl(dr[ku], (kq << 4) | c);        // d[k][c]
    float pv   = __shfl(dr[ku], (kq << 4) | k);        // d[k][k]
    float cv0  = __shfl(dr[0], (l & 48) | k);          // d[4q+u][k]
    float cv1  = __shfl(dr[1], (l & 48) | k);
    float cv2  = __shfl(dr[2], (l & 48) | k);
    float cv3  = __shfl(dr[3], (l & 48) | k);
    float rpv  = __builtin_amdgcn_rcpf(pv);
    float t1v  = rowv * rpv;
    float cva[4] = {cv0, cv1, cv2, cv3};
#pragma unroll
    for (int u = 0; u < 4; ++u) {
      bool irow = (q == kq) && (u == ku);
      float nv = irow ? ((c == k) ? rpv : t1v)
                      : ((c == k) ? (-cva[u] * rpv) : fmaf(-cva[u], t1v, dr[u]));
      dr[u] = nv;
    }
  }
}

__device__ __forceinline__ void seed_mmt(const float* dis, float dr[4], int q, int c) {
  float a0 = 0, a1 = 0, a2 = 0, a3 = 0;
#pragma unroll
  for (int kb = 0; kb < 4; ++kb) {
    float4 bc4 = *(const float4*)&dis[c * 20 + kb * 4];
    float4 r0 = *(const float4*)&dis[(q * 4 + 0) * 20 + kb * 4];
    float4 r1 = *(const float4*)&dis[(q * 4 + 1) * 20 + kb * 4];
    float4 r2 = *(const float4*)&dis[(q * 4 + 2) * 20 + kb * 4];
    float4 r3 = *(const float4*)&dis[(q * 4 + 3) * 20 + kb * 4];
    a0 += DOT4(r0, bc4); a1 += DOT4(r1, bc4); a2 += DOT4(r2, bc4); a3 += DOT4(r3, bc4);
  }
  dr[0] = a0 + (q * 4 + 0 == c ? 1e-6f : 0.f);
  dr[1] = a1 + (q * 4 + 1 == c ? 1e-6f : 0.f);
  dr[2] = a2 + (q * 4 + 2 == c ? 1e-6f : 0.f);
  dr[3] = a3 + (q * 4 + 3 == c ? 1e-6f : 0.f);
}

__device__ __forceinline__ void ric_y(const float* bbs, const float* dis, float* ys, int q, int c) {
  float y0 = 0, y1 = 0, y2 = 0, y3 = 0;
#pragma unroll
  for (int kb = 0; kb < 4; ++kb) {
    float4 bc4 = *(const float4*)&bbs[c * 20 + kb * 4];
    float4 r0 = *(const float4*)&dis[(q * 4 + 0) * 20 + kb * 4];
    float4 r1 = *(const float4*)&dis[(q * 4 + 1) * 20 + kb * 4];
    float4 r2 = *(const float4*)&dis[(q * 4 + 2) * 20 + kb * 4];
    float4 r3 = *(const float4*)&dis[(q * 4 + 3) * 20 + kb * 4];
    y0 += DOT4(r0, bc4); y1 += DOT4(r1, bc4); y2 += DOT4(r2, bc4); y3 += DOT4(r3, bc4);
  }
  ys[(q * 4 + 0) * 20 + c] = y0;
  ys[(q * 4 + 1) * 20 + c] = y1;
  ys[(q * 4 + 2) * 20 + c] = y2;
  ys[(q * 4 + 3) * 20 + c] = y3;
}

__device__ __forceinline__ void ric_dp(float dr[4], const float aar[4],
                                       const float* bbs, const float* ys, int q, int c) {
  float s0 = aar[0], s1 = aar[1], s2 = aar[2], s3 = aar[3];
#pragma unroll
  for (int kb = 0; kb < 4; ++kb) {
    float4 b0 = *(const float4*)&bbs[(q * 4 + 0) * 20 + kb * 4];
    float4 b1 = *(const float4*)&bbs[(q * 4 + 1) * 20 + kb * 4];
    float4 b2 = *(const float4*)&bbs[(q * 4 + 2) * 20 + kb * 4];
    float4 b3 = *(const float4*)&bbs[(q * 4 + 3) * 20 + kb * 4];
    float yk0 = ys[(kb * 4 + 0) * 20 + c];
    float yk1 = ys[(kb * 4 + 1) * 20 + c];
    float yk2 = ys[(kb * 4 + 2) * 20 + c];
    float yk3 = ys[(kb * 4 + 3) * 20 + c];
    s0 -= b0.x * yk0 + b0.y * yk1 + b0.z * yk2 + b0.w * yk3;
    s1 -= b1.x * yk0 + b1.y * yk1 + b1.z * yk2 + b1.w * yk3;
    s2 -= b2.x * yk0 + b2.y * yk1 + b2.z * yk2 + b2.w * yk3;
    s3 -= b3.x * yk0 + b3.y * yk1 + b3.z * yk2 + b3.w * yk3;
  }
  dr[0] = s0; dr[1] = s1; dr[2] = s2; dr[3] = s3;
}

// ---------------- K4: Riccati, 2 chunks per wave (ILP-2) ----------------
#define RIC_S 16
#define RIC_W 64
#define RIC_NB (T_STEPS / (2 * RIC_S))   // 256 blocks

__global__ __launch_bounds__(64) void riccati_wave2(
    const float* __restrict__ AA, const float* __restrict__ BBm,
    const float* __restrict__ Ccat, float* __restrict__ D)
{
  int l = threadIdx.x;
  int q = l >> 4, c = l & 15;
  int b = blockIdx.x;
  int t0a = (2 * b) * RIC_S, t0b = t0a + RIC_S;
  int twa = t0a - RIC_W; if (twa < 0) twa = 0;
  int twb = t0b - RIC_W; if (twb < 0) twb = 0;
  int tenda = t0a + RIC_S - 1, tendb = t0b + RIC_S - 1;
  int row = l >> 2, cb = (l & 3) * 4;

  __shared__ float bbsA[320], disA[320], ysA[320];
  __shared__ float bbsB[320], disB[320], ysB[320];

  // seeds: M = A_t + I -> D = M M^T + eps I (exact at t==0)
  {
    float4 va = *(const float4*)(Ccat + (size_t)twa * 768 + l * 4);
    float4 vb = *(const float4*)(Ccat + (size_t)twb * 768 + l * 4);
    float aa4[4] = {va.x, va.y, va.z, va.w};
    float bb4_[4] = {vb.x, vb.y, vb.z, vb.w};
#pragma unroll
    for (int e = 0; e < 4; ++e) {
      if (row == cb + e) { aa4[e] += 1.f; bb4_[e] += 1.f; }
    }
    *(float4*)&disA[row * 20 + cb] = *(float4*)aa4;
    *(float4*)&disB[row * 20 + cb] = *(float4*)bb4_;
  }
  __syncthreads();
  float drA[4], drB[4];
  seed_mmt(disA, drA, q, c);
  seed_mmt(disB, drB, q, c);

  for (int s = 0; ; ++s) {
    int ta = twa + s, tb = twb + s;
    if (ta >= t0a && ta <= tenda) {
#pragma unroll
      for (int u = 0; u < 4; ++u)
        D[(size_t)ta * 256 + (q * 4 + u) * 16 + c] = drA[u];
    }
    if (tb >= t0b) {
#pragma unroll
      for (int u = 0; u < 4; ++u)
        D[(size_t)tb * 256 + (q * 4 + u) * 16 + c] = drB[u];
    }
    if (tb == tendb) break;

    float4 bbA = *(const float4*)(BBm + (size_t)ta * 256 + l * 4);
    float4 bbB = *(const float4*)(BBm + (size_t)tb * 256 + l * 4);
    float aarA[4], aarB[4];
#pragma unroll
    for (int u = 0; u < 4; ++u) {
      aarA[u] = AA[(size_t)(ta + 1) * 256 + (q * 4 + u) * 16 + c];
      aarB[u] = AA[(size_t)(tb + 1) * 256 + (q * 4 + u) * 16 + c];
    }

    gj_inv(drA, l, q, c);
    gj_inv(drB, l, q, c);

    __syncthreads();
    *(float4*)&bbsA[row * 20 + cb] = bbA;
    *(float4*)&bbsB[row * 20 + cb] = bbB;
#pragma unroll
    for (int u = 0; u < 4; ++u) {
      disA[(q * 4 + u) * 20 + c] = drA[u];
      disB[(q * 4 + u) * 20 + c] = drB[u];
    }
    __syncthreads();

    ric_y(bbsA, disA, ysA, q, c);
    ric_y(bbsB, disB, ysB, q, c);
    __syncthreads();

    ric_dp(drA, aarA, bbsA, ysA, q, c);
    ric_dp(drB, aarB, bbsB, ysB, q, c);
  }
}

// ---------------- K5: per-t chol, Linv, C ----------------
__global__ __launch_bounds__(256) void chol_inv(
    const float* __restrict__ D, const float* __restrict__ BBm,
    float* __restrict__ Linv, float* __restrict__ Cmat)
{
  int t = blockIdx.x;
  int tid = threadIdx.x;
  int i = tid >> 4, j = tid & 15;
  __shared__ float d[16][17], li[16][17], rhs[16][17], bb[16][17];
  d[i][j] = D[(size_t)t * 256 + tid];
  bool has_b = (t < T_STEPS - 1);
  if (has_b) bb[i][j] = BBm[(size_t)t * 256 + tid];
  rhs[i][j] = (i == j) ? 1.f : 0.f;
  __syncthreads();
  for (int k = 0; k < 16; ++k) {
    if (tid == k * 16 + k) d[k][k] = sqrtf(d[k][k]);
    __syncthreads();
    if (j == k && i > k) d[i][k] /= d[k][k];
    __syncthreads();
    if (i > k && j > k && j <= i) d[i][j] -= d[i][k] * d[j][k];
    __syncthreads();
  }
  for (int k = 0; k < 16; ++k) {
    if (i == k) li[k][j] = rhs[k][j] / d[k][k];
    __syncthreads();
    if (i > k) rhs[i][j] -= d[i][k] * li[k][j];
    __syncthreads();
  }
  Linv[(size_t)t * 256 + tid] = li[i][j];
  if (has_b) {
    float s = 0.f;
#pragma unroll
    for (int k = 0; k < 16; ++k) s += bb[i][k] * li[j][k];
    Cmat[(size_t)t * 256 + tid] = s;
  }
}

// ---------------- xseq helpers ----------------
__device__ __forceinline__ void xstep_chunk(
    float xr[4], const float* lis, const float* cs, bool haveC, int q, int c)
{
  float tr[4];
  tr[0] = (q * 4 + 0 == c) ? 1.f : 0.f;
  tr[1] = (q * 4 + 1 == c) ? 1.f : 0.f;
  tr[2] = (q * 4 + 2 == c) ? 1.f : 0.f;
  tr[3] = (q * 4 + 3 == c) ? 1.f : 0.f;
  if (haveC) {
#pragma unroll
    for (int kb = 0; kb < 4; ++kb) {
      float4 r0 = *(const float4*)&cs[(q * 4 + 0) * 20 + kb * 4];
      float4 r1 = *(const float4*)&cs[(q * 4 + 1) * 20 + kb * 4];
      float4 r2 = *(const float4*)&cs[(q * 4 + 2) * 20 + kb * 4];
      float4 r3 = *(const float4*)&cs[(q * 4 + 3) * 20 + kb * 4];
      float a0[4] = {r0.x, r0.y, r0.z, r0.w};
      float a1[4] = {r1.x, r1.y, r1.z, r1.w};
      float a2[4] = {r2.x, r2.y, r2.z, r2.w};
      float a3[4] = {r3.x, r3.y, r3.z, r3.w};
#pragma unroll
      for (int e = 0; e < 4; ++e) {
        float xk = __shfl(xr[e], (kb << 4) | c);
        tr[0] = fmaf(-a0[e], xk, tr[0]);
        tr[1] = fmaf(-a1[e], xk, tr[1]);
        tr[2] = fmaf(-a2[e], xk, tr[2]);
        tr[3] = fmaf(-a3[e], xk, tr[3]);
      }
    }
  }
  float x0 = 0, x1 = 0, x2 = 0, x3 = 0;
#pragma unroll
  for (int kb = 0; kb < 4; ++kb) {
    float4 r0 = *(const float4*)&lis[(q * 4 + 0) * 20 + kb * 4];
    float4 r1 = *(const float4*)&lis[(q * 4 + 1) * 20 + kb * 4];
    float4 r2 = *(const float4*)&lis[(q * 4 + 2) * 20 + kb * 4];
    float4 r3 = *(const float4*)&lis[(q * 4 + 3) * 20 + kb * 4];
    float a0[4] = {r0.x, r0.y, r0.z, r0.w};
    float a1[4] = {r1.x, r1.y, r1.z, r1.w};
    float a2[4] = {r2.x, r2.y, r2.z, r2.w};
    float a3[4] = {r3.x, r3.y, r3.z, r3.w};
#pragma unroll
    for (int e = 0; e < 4; ++e) {
      float tk = __shfl(tr[e], (kb << 4) | c);
      x0 = fmaf(a0[e], tk, x0);
      x1 = fmaf(a1[e], tk, x1);
      x2 = fmaf(a2[e], tk, x2);
      x3 = fmaf(a3[e], tk, x3);
    }
  }
  xr[0] = x0; xr[1] = x1; xr[2] = x2; xr[3] = x3;
}

__device__ __forceinline__ void x_emit(
    const float xr[4], const float* __restrict__ mu, const float* __restrict__ eps,
    float* __restrict__ out, float& logacc, int t, int q, int c)
{
  float r0v = fmaxf(xr[0], 1e-5f), r1v = fmaxf(xr[1], 1e-5f);
  float r2v = fmaxf(xr[2], 1e-5f), r3v = fmaxf(xr[3], 1e-5f);
  if (q == (c >> 2)) {
    int sel = c & 3;
    float dv = sel == 0 ? r0v : (sel == 1 ? r1v : (sel == 2 ? r2v : r3v));
    logacc -= logf(dv);
  }
  float e0 = eps[(size_t)t * 16 + q * 4 + 0];
  float e1 = eps[(size_t)t * 16 + q * 4 + 1];
  float e2 = eps[(size_t)t * 16 + q * 4 + 2];
  float e3 = eps[(size_t)t * 16 + q * 4 + 3];
  float part = r0v * e0 + r1v * e1 + r2v * e2 + r3v * e3;
  part += __shfl_xor(part, 16);
  part += __shfl_xor(part, 32);
  if (q == 0) out[1 + (size_t)t * 16 + c] = mu[(size_t)t * 16 + c] + part;
}

// ---------------- K6: x recursion, 2 chunks per wave (ILP-2) ----------------
#define XS 32
#define XW 128
#define XNB (T_STEPS / (2 * XS))   // 128 blocks

__global__ __launch_bounds__(64) void xseq_wave2(
    const float* __restrict__ Linv, const float* __restrict__ Cmat,
    const float* __restrict__ mu, const float* __restrict__ eps,
    float* __restrict__ out, float* __restrict__ logdet)
{
  int l = threadIdx.x;
  int q = l >> 4, c = l & 15;
  int b = blockIdx.x;
  int t0a = (2 * b) * XS, t0b = t0a + XS;
  int tsa = t0a - XW; if (tsa < 0) tsa = 0;
  int tsb = t0b - XW; if (tsb < 0) tsb = 0;
  int enda = t0a + XS, endb = t0b + XS;
  int row = l >> 2, cb = (l & 3) * 4;
  __shared__ float lisA[320], csA[320], lisB[320], csB[320];
  float xrA[4] = {0.f, 0.f, 0.f, 0.f};
  float xrB[4] = {0.f, 0.f, 0.f, 0.f};
  float logacc = 0.f;

  int smax = endb - tsb;   // B always finishes last (or ties)
  for (int s = 0; s < smax; ++s) {
    int ta = tsa + s, tb = tsb + s;
    float4 liA = *(const float4*)(Linv + (size_t)ta * 256 + l * 4);
    float4 liB = *(const float4*)(Linv + (size_t)tb * 256 + l * 4);
    float4 cA = {0.f, 0.f, 0.f, 0.f}, cB = {0.f, 0.f, 0.f, 0.f};
    if (ta > 0) cA = *(const float4*)(Cmat + (size_t)(ta - 1) * 256 + l * 4);
    if (tb > 0) cB = *(const float4*)(Cmat + (size_t)(tb - 1) * 256 + l * 4);
    __syncthreads();
    *(float4*)&lisA[row * 20 + cb] = liA;
    *(float4*)&csA[row * 20 + cb] = cA;
    *(float4*)&lisB[row * 20 + cb] = liB;
    *(float4*)&csB[row * 20 + cb] = cB;
    __syncthreads();

    xstep_chunk(xrA, lisA, csA, ta > 0, q, c);
    xstep_chunk(xrB, lisB, csB, tb > 0, q, c);

    if (ta >= t0a && ta < enda) x_emit(xrA, mu, eps, out, logacc, ta, q, c);
    if (tb >= t0b)              x_emit(xrB, mu, eps, out, logacc, tb, q, c);
  }
#pragma unroll
  for (int off = 1; off < 64; off <<= 1) logacc += __shfl_xor(logacc, off);
  if (l == 0) atomicAdd(logdet, logacc);
}

// ---------------- K7: entropy ----------------
__global__ void finalize_entropy(const float* __restrict__ logdet, float* __restrict__ out)
{
  if (threadIdx.x == 0 && blockIdx.x == 0) {
    const double ENT = 0.5 * 1024.0 * 8192.0 * (1.0 + 1.8378770664093454);
    out[0] = (float)(ENT + (double)(*logdet));
  }
}

extern "C" void kernel_launch(void* const* d_in, const int* in_sizes, int n_in,
                              void* d_out, int out_size, void* d_ws, size_t ws_size,
                              hipStream_t stream)
{
  const float* X   = (const float*)d_in[0];
  const float* W1  = (const float*)d_in[1];
  const float* b1  = (const float*)d_in[2];
  const float* Wmu = (const float*)d_in[3];
  const float* bmu = (const float*)d_in[4];
  const float* WA  = (const float*)d_in[5];
  const float* bA  = (const float*)d_in[6];
  const float* WB  = (const float*)d_in[7];
  const float* bB  = (const float*)d_in[8];
  const float* eps = (const float*)d_in[9];
  float* out = (float*)d_out;
  char* ws  = (char*)d_ws;

  // Workspace, peak ~52.4 MB (< 59.2 MB proven-safe). Lifetime-audited:
  //  Ccat  @ 0         25165824  [K2 .. K4 seed]
  //    Xbf @ 0         16777216  [P0 .. K1]     (dead before Ccat written)
  //    W1t @ 16777216   2097152  [P0 .. K1]
  //    Cmat@ 0          8388608  [K5 .. K6]     (Ccat dead after K4)
  //  hbf   @ 25165824  16777216  [K1 .. mu_gemm]
  //    AA  @ 25165824   8388608  [K3 .. K4]     (hbf dead)
  //    BB  @ 33554432   8388608  [K3 .. K5]
  //    Linv@ 25165824   8388608  [K5 .. K6]     (AA dead after K4)
  //  D     @ 41943040   8388608  [K4 .. K5]
  //  muw   @ 50331648    524288  [K2b .. K6]
  //  logdet@ 50855936         4
  //  Wcat  @ 50856960   1572864  [P0 .. K2]
  unsigned short* Xbf  = (unsigned short*)(ws + 0);
  unsigned short* W1t  = (unsigned short*)(ws + 16777216);
  unsigned short* hbf  = (unsigned short*)(ws + 25165824);
  unsigned short* Wcat = (unsigned short*)(ws + 50856960);
  float* Ccat   = (float*)(ws + 0);
  float* Cmat   = (float*)(ws + 0);
  float* AAp    = (float*)(ws + 25165824);
  float* Linv   = (float*)(ws + 25165824);
  float* BBp    = (float*)(ws + 33554432);
  float* Dws    = (float*)(ws + 41943040);
  float* muw    = (float*)(ws + 50331648);
  float* logdet = (float*)(ws + 50855936);

  dim3 blk(256);

  // P0: bf16 conversions; WA/WBtop/WBbot transposed into one [768][1024] buffer
  to_bf16<<<dim3(8192), blk, 0, stream>>>(X, Xbf, 8192 * 1024 / 4);
  transpose_bf16<<<dim3(32, 32), blk, 0, stream>>>(W1, W1t, 1024, 1024);
  transpose_bf16<<<dim3(32, 8), blk, 0, stream>>>(WA, Wcat, 1024, 256);
  transpose_bf16<<<dim3(32, 8), blk, 0, stream>>>(WB, Wcat + 256 * 1024, 1024, 256);
  transpose_bf16<<<dim3(32, 8), blk, 0, stream>>>(WB + 1024 * 256, Wcat + 512 * 1024, 1024, 256);
  // K1: h = relu(X@W1+b1) -> bf16
  gemm_mfma<<<dim3(8, 64), blk, 0, stream>>>(Xbf, W1t, b1, 1024, nullptr, hbf, 8192, 1024, 1024, 1);
  // K2: Ccat = h @ [WA|WBt|WBb] (+bA on first 256 cols), fp32; + mu
  gemm_mfma<<<dim3(6, 64), blk, 0, stream>>>(hbf, Wcat, bA, 256, Ccat, nullptr, 8192, 768, 1024, 0);
  mu_gemm<<<dim3(512), blk, 0, stream>>>(hbf, Wmu, bmu, muw);
  // K3: AA, BB (hbf dead; AA/BB overwrite it)
  make_psd<<<dim3(T_STEPS), blk, 0, stream>>>(Ccat, bB, AAp, BBp, logdet);
  // K4: warmup Riccati, 2 chunks/wave
  riccati_wave2<<<dim3(RIC_NB), dim3(64), 0, stream>>>(AAp, BBp, Ccat, Dws);
  // K5: chol/Linv/C (AA & Ccat dead; Linv/Cmat overwrite them)
  chol_inv<<<dim3(T_STEPS), blk, 0, stream>>>(Dws, BBp, Linv, Cmat);
  // K6: x recursion, 2 chunks/wave
  xseq_wave2<<<dim3(XNB), dim3(64), 0, stream>>>(Linv, Cmat, muw, eps, out, logdet);
  // K7
  finalize_entropy<<<dim3(1), dim3(64), 0, stream>>>(logdet, out);
}

// Round 9
// 574.887 us; speedup vs baseline: 1.5949x; 1.5949x over previous
//
#include <hip/hip_runtime.h>
#include <math.h>

// SequentialVAE on MI355X.
// R8 -> R9: ILP-2 reverted (compiler serialized the dual chains — 2x regression).
// Back to R7's single-chunk riccati_wave; xseq restructured algebraically:
//   x_t = Linv_t (I - C_{t-1} x_{t-1}) == Linv_t + G_t x_{t-1},  G_t = -Linv_t C_{t-1}
// G is computed in a fully parallel kernel, so the serial x-step is ONE 16x16
// matmul (half the chain), with G/Linv prefetched one step ahead.
//
//  P0  X -> bf16; transpose->bf16 of W1; WA/WBtop/WBbot into Wcat
//  K1  MFMA bf16 gemm: h = relu(X@W1+b1) -> bf16
//  K2  MFMA bf16 gemm: Ccat = h@[WA|WBt|WBb] (+bA on cols<256) -> fp32 [8192][768]
//      + mu = h@Wmu+bmu
//  K3  make_psd: AA_t, BB_t from Ccat slices
//  K4  riccati_wave: 512 chunks x (S=16, W=64), 1 wave each (proven R7 code)
//  K5  chol_inv per t: L=chol(D), Linv=L^{-1}, C = BB Linv^T
//  K5b gmat: G_t = -Linv_t C_{t-1} (parallel), G_0 = 0
//  K6  xseq_g: 256 chunks x (XS=32, XW=128), x_t = Linv_t + G_t x_{t-1}, prefetched
//  K7  entropy = logdet + DX*T/2*(1+log(2pi))

#define T_STEPS 8192
#define DXX 1024

typedef __bf16 bf16x8 __attribute__((ext_vector_type(8)));
typedef float f32x4 __attribute__((ext_vector_type(4)));
typedef unsigned short u16x8 __attribute__((ext_vector_type(8)));
typedef unsigned short u16x4 __attribute__((ext_vector_type(4)));

#define DOT4(r, b) ((r).x*(b).x + (r).y*(b).y + (r).z*(b).z + (r).w*(b).w)

__device__ __forceinline__ unsigned short f2bf(float v) {
  unsigned int u = __float_as_uint(v);
  unsigned int r = (u + 0x7FFFu + ((u >> 16) & 1u)) >> 16;   // RN-even
  return (unsigned short)r;
}
__device__ __forceinline__ float bf2f(unsigned short b) {
  return __uint_as_float(((unsigned int)b) << 16);
}

// ---------------- P0a: elementwise fp32 -> bf16 ----------------
__global__ __launch_bounds__(256) void to_bf16(
    const float* __restrict__ src, unsigned short* __restrict__ dst, int n4)
{
  int idx = blockIdx.x * 256 + threadIdx.x;
  if (idx >= n4) return;
  float4 v = ((const float4*)src)[idx];
  u16x4 h;
  h[0] = f2bf(v.x); h[1] = f2bf(v.y); h[2] = f2bf(v.z); h[3] = f2bf(v.w);
  *(u16x4*)(dst + (size_t)idx * 4) = h;
}

// ---------------- P0b: transpose [K][N] -> [N][K] + bf16 ----------------
__global__ __launch_bounds__(256) void transpose_bf16(
    const float* __restrict__ W, unsigned short* __restrict__ Tt, int K, int N)
{
  __shared__ float tile[32][33];
  int k0 = blockIdx.x * 32, n0 = blockIdx.y * 32;
  int c = threadIdx.x & 31, r = threadIdx.x >> 5;  // r in 0..7
#pragma unroll
  for (int e = 0; e < 4; ++e)
    tile[r + 8 * e][c] = W[(size_t)(k0 + r + 8 * e) * N + n0 + c];
  __syncthreads();
#pragma unroll
  for (int e = 0; e < 4; ++e)
    Tt[(size_t)(n0 + r + 8 * e) * K + k0 + c] = f2bf(tile[c][r + 8 * e]);
}

// ---------------- K1/K2: MFMA bf16 GEMM ----------------
#define LDT 40

__global__ __launch_bounds__(256) void gemm_mfma(
    const unsigned short* __restrict__ Abf, const unsigned short* __restrict__ Bbf,
    const float* __restrict__ bias, int biasN, float* __restrict__ outF,
    unsigned short* __restrict__ outBf, int M, int N, int K, int mode)
{
  __shared__ __align__(16) unsigned short At[128 * LDT];
  __shared__ __align__(16) unsigned short Bt[128 * LDT];
  int tid = threadIdx.x;
  int l = tid & 63;
  int w = tid >> 6;
  int wm = w >> 1, wn = w & 1;
  int lane15 = l & 15, quad = l >> 4;
  int bm = blockIdx.y * 128, bn = blockIdx.x * 128;
  int srow = tid >> 1, shalf = tid & 1;
  const size_t aRowOff = (size_t)(bm + srow) * K;
  const size_t bRowOff = (size_t)(bn + srow) * K;

  f32x4 acc[4][4];
#pragma unroll
  for (int mi = 0; mi < 4; ++mi)
#pragma unroll
    for (int ni = 0; ni < 4; ++ni) acc[mi][ni] = (f32x4){0.f, 0.f, 0.f, 0.f};

  for (int k0 = 0; k0 < K; k0 += 32) {
    u16x8 a0 = *(const u16x8*)(Abf + aRowOff + k0 + shalf * 16);
    u16x8 a1 = *(const u16x8*)(Abf + aRowOff + k0 + shalf * 16 + 8);
    u16x8 b0 = *(const u16x8*)(Bbf + bRowOff + k0 + shalf * 16);
    u16x8 b1 = *(const u16x8*)(Bbf + bRowOff + k0 + shalf * 16 + 8);
    __syncthreads();
    *(u16x8*)&At[srow * LDT + shalf * 16] = a0;
    *(u16x8*)&At[srow * LDT + shalf * 16 + 8] = a1;
    *(u16x8*)&Bt[srow * LDT + shalf * 16] = b0;
    *(u16x8*)&Bt[srow * LDT + shalf * 16 + 8] = b1;
    __syncthreads();
    bf16x8 af[4], bfr[4];
#pragma unroll
    for (int mi = 0; mi < 4; ++mi)
      af[mi] = *(const bf16x8*)&At[(wm * 64 + mi * 16 + lane15) * LDT + quad * 8];
#pragma unroll
    for (int ni = 0; ni < 4; ++ni)
      bfr[ni] = *(const bf16x8*)&Bt[(wn * 64 + ni * 16 + lane15) * LDT + quad * 8];
#pragma unroll
    for (int mi = 0; mi < 4; ++mi)
#pragma unroll
      for (int ni = 0; ni < 4; ++ni)
        acc[mi][ni] = __builtin_amdgcn_mfma_f32_16x16x32_bf16(af[mi], bfr[ni], acc[mi][ni], 0, 0, 0);
  }

#pragma unroll
  for (int mi = 0; mi < 4; ++mi) {
#pragma unroll
    for (int ni = 0; ni < 4; ++ni) {
      int gc = bn + wn * 64 + ni * 16 + lane15;
      float bv = (bias && gc < biasN) ? bias[gc] : 0.f;
#pragma unroll
      for (int r = 0; r < 4; ++r) {
        int gr = bm + wm * 64 + mi * 16 + quad * 4 + r;
        float v = acc[mi][ni][r] + bv;
        if (mode == 1) {
          outBf[(size_t)gr * N + gc] = f2bf(fmaxf(v, 0.f));
        } else {
          outF[(size_t)gr * N + gc] = v;
        }
      }
    }
  }
}

// ---------------- K2b: mu = h @ Wmu + bmu ----------------
__global__ __launch_bounds__(256) void mu_gemm(
    const unsigned short* __restrict__ hbf, const float* __restrict__ Wmu,
    const float* __restrict__ bmu, float* __restrict__ mu)
{
  int idx = blockIdx.x * 256 + threadIdx.x;
  int t = idx >> 4, j = idx & 15;
  const u16x8* ph = (const u16x8*)(hbf + (size_t)t * 1024);
  float s = bmu[j];
#pragma unroll 2
  for (int k8 = 0; k8 < 128; ++k8) {
    u16x8 hv = ph[k8];
#pragma unroll
    for (int e = 0; e < 8; ++e)
      s = fmaf(bf2f(hv[e]), Wmu[(k8 * 8 + e) * 16 + j], s);
  }
  mu[idx] = s;
}

// ---------------- K3: AA_t, BB_t from Ccat (stride 768: A|Qtop|Qbot) ----------------
__global__ __launch_bounds__(256) void make_psd(
    const float* __restrict__ Ccat, const float* __restrict__ bB,
    float* __restrict__ AA, float* __restrict__ BBm, float* __restrict__ logdet)
{
  int t = blockIdx.x;
  int tid = threadIdx.x;
  int i = tid >> 4, j = tid & 15;
  if (t == 0 && tid == 0) *logdet = 0.f;
  __shared__ float a[16][17], bp[16][17], bq[16][17];
  a[i][j] = Ccat[(size_t)t * 768 + tid] + (i == j ? 1.f : 0.f);
  bp[i][j] = (t >= 1) ? (Ccat[(size_t)t * 768 + 256 + tid] + Ccat[(size_t)(t - 1) * 768 + 512 + tid] + bB[tid]) : 0.f;
  bool has_b = (t < T_STEPS - 1);
  if (has_b) bq[i][j] = Ccat[(size_t)(t + 1) * 768 + 256 + tid] + Ccat[(size_t)t * 768 + 512 + tid] + bB[tid];
  __syncthreads();
  float s = (i == j) ? 1e-6f : 0.f;
#pragma unroll
  for (int k = 0; k < 16; ++k) s += a[i][k] * a[j][k] + bp[i][k] * bp[j][k];
  AA[(size_t)t * 256 + tid] = s;
  if (has_b) {
    float s2 = 0.f;
#pragma unroll
    for (int k = 0; k < 16; ++k) s2 += bq[i][k] * a[j][k];
    BBm[(size_t)t * 256 + tid] = s2;
  }
}

// ---------------- K4: wave-level chunked Riccati (proven R7 code) ----------------
#define RIC_S 16
#define RIC_W 64
#define RIC_NCH (T_STEPS / RIC_S)   // 512

__global__ __launch_bounds__(64) void riccati_wave(
    const float* __restrict__ AA, const float* __restrict__ BBm,
    const float* __restrict__ Ccat, float* __restrict__ D)
{
  int l = threadIdx.x;
  int q = l >> 4, c = l & 15;
  int p = blockIdx.x;
  int t0 = p * RIC_S;
  int tw = t0 - RIC_W; if (tw < 0) tw = 0;
  int tend = t0 + RIC_S - 1;
  int row = l >> 2, cb = (l & 3) * 4;

  __shared__ float bbs[320], dis[320], ys[320];

  // seed: M = A[tw] + I (Ccat cols 0..255); D = M M^T + 1e-6 I (exact at tw==0)
  {
    float4 v = *(const float4*)(Ccat + (size_t)tw * 768 + l * 4);
    float va[4] = {v.x, v.y, v.z, v.w};
#pragma unroll
    for (int e = 0; e < 4; ++e) if (row == cb + e) va[e] += 1.f;
    *(float4*)&dis[row * 20 + cb] = *(float4*)va;
  }
  __syncthreads();
  float dr[4];
  {
    float a0 = 0, a1 = 0, a2 = 0, a3 = 0;
#pragma unroll
    for (int kb = 0; kb < 4; ++kb) {
      float4 bc4 = *(const float4*)&dis[c * 20 + kb * 4];
      float4 r0 = *(const float4*)&dis[(q * 4 + 0) * 20 + kb * 4];
      float4 r1 = *(const float4*)&dis[(q * 4 + 1) * 20 + kb * 4];
      float4 r2 = *(const float4*)&dis[(q * 4 + 2) * 20 + kb * 4];
      float4 r3 = *(const float4*)&dis[(q * 4 + 3) * 20 + kb * 4];
      a0 += DOT4(r0, bc4); a1 += DOT4(r1, bc4); a2 += DOT4(r2, bc4); a3 += DOT4(r3, bc4);
    }
    dr[0] = a0 + (q * 4 + 0 == c ? 1e-6f : 0.f);
    dr[1] = a1 + (q * 4 + 1 == c ? 1e-6f : 0.f);
    dr[2] = a2 + (q * 4 + 2 == c ? 1e-6f : 0.f);
    dr[3] = a3 + (q * 4 + 3 == c ? 1e-6f : 0.f);
  }

  for (int t = tw; ; ++t) {
    if (t >= t0) {
#pragma unroll
      for (int u = 0; u < 4; ++u)
        D[(size_t)t * 256 + (q * 4 + u) * 16 + c] = dr[u];
    }
    if (t == tend) break;
    float4 bb4 = *(const float4*)(BBm + (size_t)t * 256 + l * 4);
    float aar[4];
#pragma unroll
    for (int u = 0; u < 4; ++u)
      aar[u] = AA[(size_t)(t + 1) * 256 + (q * 4 + u) * 16 + c];

    // Gauss-Jordan inverse of SPD d, in registers via shuffles
#pragma unroll
    for (int k = 0; k < 16; ++k) {
      const int kq = k >> 2, ku = k & 3;
      float rowv = __shfl(dr[ku], (kq << 4) | c);
      float pv   = __shfl(dr[ku], (kq << 4) | k);
      float cv0  = __shfl(dr[0], (l & 48) | k);
      float cv1  = __shfl(dr[1], (l & 48) | k);
      float cv2  = __shfl(dr[2], (l & 48) | k);
      float cv3  = __shfl(dr[3], (l & 48) | k);
      float rpv  = __builtin_amdgcn_rcpf(pv);
      float t1v  = rowv * rpv;
      float cva[4] = {cv0, cv1, cv2, cv3};
#pragma unroll
      for (int u = 0; u < 4; ++u) {
        bool irow = (q == kq) && (u == ku);
        float nv = irow ? ((c == k) ? rpv : t1v)
                        : ((c == k) ? (-cva[u] * rpv) : fmaf(-cva[u], t1v, dr[u]));
        dr[u] = nv;
      }
    }

    __syncthreads();
    *(float4*)&bbs[row * 20 + cb] = bb4;
#pragma unroll
    for (int u = 0; u < 4; ++u) dis[(q * 4 + u) * 20 + c] = dr[u];
    __syncthreads();

    // y[i][c] = sum_k Dinv[i][k] * bb[c][k]
    float y0 = 0, y1 = 0, y2 = 0, y3 = 0;
#pragma unroll
    for (int kb = 0; kb < 4; ++kb) {
      float4 bc4 = *(const float4*)&bbs[c * 20 + kb * 4];
      float4 r0 = *(const float4*)&dis[(q * 4 + 0) * 20 + kb * 4];
      float4 r1 = *(const float4*)&dis[(q * 4 + 1) * 20 + kb * 4];
      float4 r2 = *(const float4*)&dis[(q * 4 + 2) * 20 + kb * 4];
      float4 r3 = *(const float4*)&dis[(q * 4 + 3) * 20 + kb * 4];
      y0 += DOT4(r0, bc4); y1 += DOT4(r1, bc4); y2 += DOT4(r2, bc4); y3 += DOT4(r3, bc4);
    }
    ys[(q * 4 + 0) * 20 + c] = y0;
    ys[(q * 4 + 1) * 20 + c] = y1;
    ys[(q * 4 + 2) * 20 + c] = y2;
    ys[(q * 4 + 3) * 20 + c] = y3;
    __syncthreads();

    // d'[i][c] = aa[i][c] - sum_k bb[i][k] * y[k][c]
    float s0 = aar[0], s1 = aar[1], s2 = aar[2], s3 = aar[3];
#pragma unroll
    for (int kb = 0; kb < 4; ++kb) {
      float4 b0 = *(const float4*)&bbs[(q * 4 + 0) * 20 + kb * 4];
      float4 b1 = *(const float4*)&bbs[(q * 4 + 1) * 20 + kb * 4];
      float4 b2 = *(const float4*)&bbs[(q * 4 + 2) * 20 + kb * 4];
      float4 b3 = *(const float4*)&bbs[(q * 4 + 3) * 20 + kb * 4];
      float yk0 = ys[(kb * 4 + 0) * 20 + c];
      float yk1 = ys[(kb * 4 + 1) * 20 + c];
      float yk2 = ys[(kb * 4 + 2) * 20 + c];
      float yk3 = ys[(kb * 4 + 3) * 20 + c];
      s0 -= b0.x * yk0 + b0.y * yk1 + b0.z * yk2 + b0.w * yk3;
      s1 -= b1.x * yk0 + b1.y * yk1 + b1.z * yk2 + b1.w * yk3;
      s2 -= b2.x * yk0 + b2.y * yk1 + b2.z * yk2 + b2.w * yk3;
      s3 -= b3.x * yk0 + b3.y * yk1 + b3.z * yk2 + b3.w * yk3;
    }
    dr[0] = s0; dr[1] = s1; dr[2] = s2; dr[3] = s3;
  }
}

// ---------------- K5: per-t chol, Linv, C ----------------
__global__ __launch_bounds__(256) void chol_inv(
    const float* __restrict__ D, const float* __restrict__ BBm,
    float* __restrict__ Linv, float* __restrict__ Cmat)
{
  int t = blockIdx.x;
  int tid = threadIdx.x;
  int i = tid >> 4, j = tid & 15;
  __shared__ float d[16][17], li[16][17], rhs[16][17], bb[16][17];
  d[i][j] = D[(size_t)t * 256 + tid];
  bool has_b = (t < T_STEPS - 1);
  if (has_b) bb[i][j] = BBm[(size_t)t * 256 + tid];
  rhs[i][j] = (i == j) ? 1.f : 0.f;
  __syncthreads();
  for (int k = 0; k < 16; ++k) {
    if (tid == k * 16 + k) d[k][k] = sqrtf(d[k][k]);
    __syncthreads();
    if (j == k && i > k) d[i][k] /= d[k][k];
    __syncthreads();
    if (i > k && j > k && j <= i) d[i][j] -= d[i][k] * d[j][k];
    __syncthreads();
  }
  for (int k = 0; k < 16; ++k) {
    if (i == k) li[k][j] = rhs[k][j] / d[k][k];
    __syncthreads();
    if (i > k) rhs[i][j] -= d[i][k] * li[k][j];
    __syncthreads();
  }
  Linv[(size_t)t * 256 + tid] = li[i][j];
  if (has_b) {
    float s = 0.f;
#pragma unroll
    for (int k = 0; k < 16; ++k) s += bb[i][k] * li[j][k];
    Cmat[(size_t)t * 256 + tid] = s;
  }
}

// ---------------- K5b: G_t = -Linv_t C_{t-1} (parallel), G_0 = 0 ----------------
__global__ __launch_bounds__(256) void gmat_kernel(
    const float* __restrict__ Linv, const float* __restrict__ Cmat,
    float* __restrict__ Gmat)
{
  int t = blockIdx.x;
  int tid = threadIdx.x;
  int i = tid >> 4, j = tid & 15;
  if (t == 0) { Gmat[tid] = 0.f; return; }
  __shared__ float li[16][17], cm[16][17];
  li[i][j] = Linv[(size_t)t * 256 + tid];
  cm[i][j] = Cmat[(size_t)(t - 1) * 256 + tid];
  __syncthreads();
  float s = 0.f;
#pragma unroll
  for (int k = 0; k < 16; ++k) s -= li[i][k] * cm[k][j];
  Gmat[(size_t)t * 256 + tid] = s;
}

// ---------------- K6: x recursion, one matmul per step, prefetched ----------------
#define XS 32
#define XW 128
#define XNCH (T_STEPS / XS)   // 256

__global__ __launch_bounds__(64) void xseq_g(
    const float* __restrict__ Linv, const float* __restrict__ Gmat,
    const float* __restrict__ mu, const float* __restrict__ eps,
    float* __restrict__ out, float* __restrict__ logdet)
{
  int l = threadIdx.x;
  int q = l >> 4, c = l & 15;
  int p = blockIdx.x;
  int t0 = p * XS;
  int ts = t0 - XW; if (ts < 0) ts = 0;   // ts==0 exact (G_0 = 0)
  int row = l >> 2, cb = (l & 3) * 4;
  __shared__ float gs[320];
  float xr[4] = {0.f, 0.f, 0.f, 0.f};    // x[4q+u][c]
  float logacc = 0.f;

  // prefetch t = ts: G row-layout, Linv direct (q,c) layout
  float4 g4 = *(const float4*)(Gmat + (size_t)ts * 256 + l * 4);
  float li[4];
#pragma unroll
  for (int u = 0; u < 4; ++u)
    li[u] = Linv[(size_t)ts * 256 + (q * 4 + u) * 16 + c];

  for (int t = ts; t < t0 + XS; ++t) {
    float4 g4n = {0.f, 0.f, 0.f, 0.f};
    float lin[4] = {0.f, 0.f, 0.f, 0.f};
    if (t + 1 < t0 + XS) {   // issue next step's loads now; consumed next iter
      g4n = *(const float4*)(Gmat + (size_t)(t + 1) * 256 + l * 4);
#pragma unroll
      for (int u = 0; u < 4; ++u)
        lin[u] = Linv[(size_t)(t + 1) * 256 + (q * 4 + u) * 16 + c];
    }
    __syncthreads();                       // prior reads of gs complete
    *(float4*)&gs[row * 20 + cb] = g4;
    __syncthreads();

    // x_new[4q+u][c] = Linv[4q+u][c] + sum_k G[4q+u][k] * x[k][c]
    float x0 = li[0], x1 = li[1], x2 = li[2], x3 = li[3];
#pragma unroll
    for (int kb = 0; kb < 4; ++kb) {
      float4 r0 = *(const float4*)&gs[(q * 4 + 0) * 20 + kb * 4];
      float4 r1 = *(const float4*)&gs[(q * 4 + 1) * 20 + kb * 4];
      float4 r2 = *(const float4*)&gs[(q * 4 + 2) * 20 + kb * 4];
      float4 r3 = *(const float4*)&gs[(q * 4 + 3) * 20 + kb * 4];
      float a0[4] = {r0.x, r0.y, r0.z, r0.w};
      float a1[4] = {r1.x, r1.y, r1.z, r1.w};
      float a2[4] = {r2.x, r2.y, r2.z, r2.w};
      float a3[4] = {r3.x, r3.y, r3.z, r3.w};
#pragma unroll
      for (int e = 0; e < 4; ++e) {
        float xk = __shfl(xr[e], (kb << 4) | c);   // x[4kb+e][c]
        x0 = fmaf(a0[e], xk, x0);
        x1 = fmaf(a1[e], xk, x1);
        x2 = fmaf(a2[e], xk, x2);
        x3 = fmaf(a3[e], xk, x3);
      }
    }
    xr[0] = x0; xr[1] = x1; xr[2] = x2; xr[3] = x3;

    if (t >= t0) {
      float r0v = fmaxf(x0, 1e-5f), r1v = fmaxf(x1, 1e-5f);
      float r2v = fmaxf(x2, 1e-5f), r3v = fmaxf(x3, 1e-5f);
      if (q == (c >> 2)) {   // lane holding diagonal r[c][c] at u=c&3
        int sel = c & 3;
        float dv = sel == 0 ? r0v : (sel == 1 ? r1v : (sel == 2 ? r2v : r3v));
        logacc -= logf(dv);
      }
      float e0 = eps[(size_t)t * 16 + q * 4 + 0];
      float e1 = eps[(size_t)t * 16 + q * 4 + 1];
      float e2 = eps[(size_t)t * 16 + q * 4 + 2];
      float e3 = eps[(size_t)t * 16 + q * 4 + 3];
      float part = r0v * e0 + r1v * e1 + r2v * e2 + r3v * e3;
      part += __shfl_xor(part, 16);
      part += __shfl_xor(part, 32);
      if (q == 0) out[1 + (size_t)t * 16 + c] = mu[(size_t)t * 16 + c] + part;
    }
    g4 = g4n;
    li[0] = lin[0]; li[1] = lin[1]; li[2] = lin[2]; li[3] = lin[3];
  }
#pragma unroll
  for (int off = 1; off < 64; off <<= 1) logacc += __shfl_xor(logacc, off);
  if (l == 0) atomicAdd(logdet, logacc);
}

// ---------------- K7: entropy ----------------
__global__ void finalize_entropy(const float* __restrict__ logdet, float* __restrict__ out)
{
  if (threadIdx.x == 0 && blockIdx.x == 0) {
    const double ENT = 0.5 * 1024.0 * 8192.0 * (1.0 + 1.8378770664093454);
    out[0] = (float)(ENT + (double)(*logdet));
  }
}

extern "C" void kernel_launch(void* const* d_in, const int* in_sizes, int n_in,
                              void* d_out, int out_size, void* d_ws, size_t ws_size,
                              hipStream_t stream)
{
  const float* X   = (const float*)d_in[0];
  const float* W1  = (const float*)d_in[1];
  const float* b1  = (const float*)d_in[2];
  const float* Wmu = (const float*)d_in[3];
  const float* bmu = (const float*)d_in[4];
  const float* WA  = (const float*)d_in[5];
  const float* bA  = (const float*)d_in[6];
  const float* WB  = (const float*)d_in[7];
  const float* bB  = (const float*)d_in[8];
  const float* eps = (const float*)d_in[9];
  float* out = (float*)d_out;
  char* ws  = (char*)d_ws;

  // Workspace, peak ~52.4 MB (< 59.2 MB proven-safe). Lifetime-audited:
  //  Ccat  @ 0         25165824  [K2 .. K4 seed]
  //    Xbf @ 0         16777216  [P0 .. K1]
  //    W1t @ 16777216   2097152  [P0 .. K1]
  //    Cmat@ 0          8388608  [K5 .. K5b]    (Ccat dead after K4)
  //  hbf   @ 25165824  16777216  [K1 .. K2b]
  //    AA  @ 25165824   8388608  [K3 .. K4]     (hbf dead)
  //    BB  @ 33554432   8388608  [K3 .. K5]
  //    Linv@ 25165824   8388608  [K5 .. K6]     (AA dead after K4)
  //  D     @ 41943040   8388608  [K4 .. K5]
  //    Gmat@ 41943040   8388608  [K5b .. K6]    (D dead after K5)
  //  muw   @ 50331648    524288  [K2b .. K6]
  //  logdet@ 50855936         4
  //  Wcat  @ 50856960   1572864  [P0 .. K2]
  unsigned short* Xbf  = (unsigned short*)(ws + 0);
  unsigned short* W1t  = (unsigned short*)(ws + 16777216);
  unsigned short* hbf  = (unsigned short*)(ws + 25165824);
  unsigned short* Wcat = (unsigned short*)(ws + 50856960);
  float* Ccat   = (float*)(ws + 0);
  float* Cmat   = (float*)(ws + 0);
  float* AAp    = (float*)(ws + 25165824);
  float* Linv   = (float*)(ws + 25165824);
  float* BBp    = (float*)(ws + 33554432);
  float* Dws    = (float*)(ws + 41943040);
  float* Gmat   = (float*)(ws + 41943040);
  float* muw    = (float*)(ws + 50331648);
  float* logdet = (float*)(ws + 50855936);

  dim3 blk(256);

  // P0: bf16 conversions; WA/WBtop/WBbot transposed into one [768][1024] buffer
  to_bf16<<<dim3(8192), blk, 0, stream>>>(X, Xbf, 8192 * 1024 / 4);
  transpose_bf16<<<dim3(32, 32), blk, 0, stream>>>(W1, W1t, 1024, 1024);
  transpose_bf16<<<dim3(32, 8), blk, 0, stream>>>(WA, Wcat, 1024, 256);
  transpose_bf16<<<dim3(32, 8), blk, 0, stream>>>(WB, Wcat + 256 * 1024, 1024, 256);
  transpose_bf16<<<dim3(32, 8), blk, 0, stream>>>(WB + 1024 * 256, Wcat + 512 * 1024, 1024, 256);
  // K1: h = relu(X@W1+b1) -> bf16
  gemm_mfma<<<dim3(8, 64), blk, 0, stream>>>(Xbf, W1t, b1, 1024, nullptr, hbf, 8192, 1024, 1024, 1);
  // K2: Ccat = h @ [WA|WBt|WBb] (+bA on first 256 cols), fp32; + mu
  gemm_mfma<<<dim3(6, 64), blk, 0, stream>>>(hbf, Wcat, bA, 256, Ccat, nullptr, 8192, 768, 1024, 0);
  mu_gemm<<<dim3(512), blk, 0, stream>>>(hbf, Wmu, bmu, muw);
  // K3: AA, BB (hbf dead; AA/BB overwrite it)
  make_psd<<<dim3(T_STEPS), blk, 0, stream>>>(Ccat, bB, AAp, BBp, logdet);
  // K4: warmup Riccati (single chunk per wave — proven R7 structure)
  riccati_wave<<<dim3(RIC_NCH), dim3(64), 0, stream>>>(AAp, BBp, Ccat, Dws);
  // K5: chol/Linv/C (AA & Ccat dead; Linv/Cmat overwrite them)
  chol_inv<<<dim3(T_STEPS), blk, 0, stream>>>(Dws, BBp, Linv, Cmat);
  // K5b: G = -Linv C_prev (D dead; Gmat overwrites it)
  gmat_kernel<<<dim3(T_STEPS), blk, 0, stream>>>(Linv, Cmat, Gmat);
  // K6: x recursion, one matmul per step, prefetched
  xseq_g<<<dim3(XNCH), dim3(64), 0, stream>>>(Linv, Gmat, muw, eps, out, logdet);
  // K7
  finalize_entropy<<<dim3(1), dim3(64), 0, stream>>>(logdet, out);
}